// Round 1
// baseline (844.732 us; speedup 1.0000x reference)
//
#include <hip/hip_runtime.h>
#include <math.h>

#define GN  4
#define MCN 100
#define BN  512
#define INN 456
#define HN  400
#define ON  10

// softplus(s)^2, numerically stable
__device__ __forceinline__ float sp2f(float s) {
    float l = log1pf(__expf(-fabsf(s)));
    float r = fmaxf(s, 0.0f) + l;
    return r * r;
}

// ---------------- kernel 0a: x -> xT, x^2 -> xxT (tiled transpose) ----------------
__global__ __launch_bounds__(256) void k_transpose(
    const float* __restrict__ x, float* __restrict__ xT, float* __restrict__ xxT) {
    __shared__ float tile[64][65];
    int it = blockIdx.x;           // i tile (8 tiles, tail: 456 = 7*64 + 8)
    int bt = blockIdx.y;           // b tile (8 tiles of 64)
    int tx = threadIdx.x & 63;
    int ty = threadIdx.x >> 6;     // 0..3
    int i_in = it * 64 + tx;
    #pragma unroll
    for (int r = 0; r < 16; ++r) {
        int row = r * 4 + ty;
        int b = bt * 64 + row;
        tile[row][tx] = (i_in < INN) ? x[b * INN + i_in] : 0.0f;
    }
    __syncthreads();
    #pragma unroll
    for (int r = 0; r < 16; ++r) {
        int row = r * 4 + ty;
        int i = it * 64 + row;
        if (i < INN) {
            float v = tile[tx][row];           // stride 65 -> conflict-free
            xT[i * BN + bt * 64 + tx]  = v;
            xxT[i * BN + bt * 64 + tx] = v * v;
        }
    }
}

// ---------------- kernel 0b: sp1 = softplus(sigma1)^2 ----------------
__global__ __launch_bounds__(256) void k_sp1(
    const float* __restrict__ sigma1, float* __restrict__ sp1) {
    int idx = blockIdx.x * 256 + threadIdx.x;
    const int n4 = GN * INN * HN / 4;   // 182400
    if (idx < n4) {
        float4 s = ((const float4*)sigma1)[idx];
        float4 o;
        o.x = sp2f(s.x); o.y = sp2f(s.y); o.z = sp2f(s.z); o.w = sp2f(s.w);
        ((float4*)sp1)[idx] = o;
    }
}

// ---------------- kernel 1: A = x@mu1, S = sqrt((x*x)@sp1) ----------------
// lane = h (coalesced vector loads of mu1/sp1), 8 b's per wave via wave-uniform
// scalar loads of xT/xxT (one SGPR operand per v_fma).
__global__ __launch_bounds__(256) void k_layer1(
    const float* __restrict__ xT, const float* __restrict__ xxT,
    const float* __restrict__ mu1, const float* __restrict__ sp1,
    float* __restrict__ A, float* __restrict__ S) {
    int bt = blockIdx.x;            // 0..15
    int ht = blockIdx.y;            // 0..6
    int g  = blockIdx.z;            // 0..3
    int lane = threadIdx.x & 63;
    int wv   = threadIdx.x >> 6;    // 0..3
    int h = ht * 64 + lane;
    bool hv = h < HN;
    int hc = hv ? h : (HN - 1);     // clamp so masked lanes stay in-bounds
    int b0 = __builtin_amdgcn_readfirstlane(bt * 32 + wv * 8);
    const float* mp = mu1 + (size_t)g * INN * HN + hc;
    const float* pp = sp1 + (size_t)g * INN * HN + hc;
    float accA[8], accD[8];
    #pragma unroll
    for (int j = 0; j < 8; ++j) { accA[j] = 0.0f; accD[j] = 0.0f; }
    #pragma unroll 4
    for (int k = 0; k < INN; ++k) {
        float a = mp[(size_t)k * HN];
        float p = pp[(size_t)k * HN];
        const float* xk  = xT  + k * BN + b0;   // wave-uniform -> s_load
        const float* xxk = xxT + k * BN + b0;
        #pragma unroll
        for (int j = 0; j < 8; ++j) {
            accA[j] = fmaf(a, xk[j],  accA[j]);
            accD[j] = fmaf(p, xxk[j], accD[j]);
        }
    }
    if (hv) {
        #pragma unroll
        for (int j = 0; j < 8; ++j) {
            size_t o = ((size_t)g * BN + (b0 + j)) * HN + h;
            A[o] = accA[j];
            S[o] = sqrtf(accD[j]);
        }
    }
}

// ---------------- kernel 2: layer 2 + softmax + MC mean ----------------
// block = (g,b). 320 threads = 20 row-groups (TM=5 MC rows each) x 16 k-chunks.
// zeta1 read direct from global: 16 lanes x 16 consecutive floats = 64B aligned runs.
// Weights in LDS rows of 20 floats (80B stride -> 2-way bank aliasing = free),
// read as 5 x ds_read_b128, amortized over 5 MC rows per thread.
__global__ __launch_bounds__(320, 3) void k_layer2(
    const float* __restrict__ A, const float* __restrict__ S,
    const float* __restrict__ mu3, const float* __restrict__ sigma3,
    const float* __restrict__ zeta1, const float* __restrict__ zeta3,
    float* __restrict__ out) {
    int b = blockIdx.x;   // 0..511
    int g = blockIdx.y;   // 0..3

    __shared__ float as_s[2 * HN];      // [h][2] = {A, S}
    __shared__ float wv_s[HN * 20];     // [h][20] = {w0..3, v0..3, w4..7, v4..7, w8,w9,v8,v9}
    __shared__ float outsh[20][ON];

    int t = threadIdx.x;

    // stage A,S (coalesced)
    for (int i = t; i < HN; i += 320) {
        size_t src = ((size_t)g * BN + b) * HN + i;
        as_s[2 * i]     = A[src];
        as_s[2 * i + 1] = S[src];
    }
    // stage mu3 and sp2(sigma3) into chunked layout
    for (int i = t; i < HN * ON; i += 320) {
        int h = i / ON, o = i % ON;
        int wslot = (o < 4) ? o       : (o < 8) ? (4 + o) : (8 + o);   // 0-3, 8-11, 16-17
        int vslot = (o < 4) ? (4 + o) : (o < 8) ? (8 + o) : (10 + o);  // 4-7, 12-15, 18-19
        size_t src = (size_t)(g * HN + h) * ON + o;
        wv_s[h * 20 + wslot] = mu3[src];
        wv_s[h * 20 + vslot] = sp2f(sigma3[src]);
    }
    __syncthreads();

    int rg = t >> 4;    // 0..19  (row group: m = rg + 20*i)
    int kc = t & 15;    // 0..15  (k = kc + 16*j)

    float accg[5][ON], accd[5][ON];
    #pragma unroll
    for (int i = 0; i < 5; ++i)
        #pragma unroll
        for (int o = 0; o < ON; ++o) { accg[i][o] = 0.0f; accd[i][o] = 0.0f; }

    const float* zp[5];
    #pragma unroll
    for (int i = 0; i < 5; ++i) {
        int m = rg + 20 * i;
        zp[i] = zeta1 + ((size_t)(g * MCN + m) * BN + b) * HN + kc;
    }

    // prefetch depth-1 pipeline over j
    float zc[5];
    #pragma unroll
    for (int i = 0; i < 5; ++i) zc[i] = zp[i][0];

    #pragma unroll 1
    for (int j = 0; j < 25; ++j) {
        float zn[5];
        if (j < 24) {
            #pragma unroll
            for (int i = 0; i < 5; ++i) zn[i] = zp[i][16 * (j + 1)];
        } else {
            #pragma unroll
            for (int i = 0; i < 5; ++i) zn[i] = 0.0f;
        }
        int k = kc + 16 * j;
        float2 as = *(const float2*)(as_s + 2 * k);
        const float* wr = wv_s + k * 20;
        float4 w03 = *(const float4*)(wr);
        float4 v03 = *(const float4*)(wr + 4);
        float4 w47 = *(const float4*)(wr + 8);
        float4 v47 = *(const float4*)(wr + 12);
        float4 t4  = *(const float4*)(wr + 16);  // w8 w9 v8 v9
        #pragma unroll
        for (int i = 0; i < 5; ++i) {
            float hval = fmaxf(0.0f, fmaf(as.y, zc[i], as.x));
            float h2 = hval * hval;
            accg[i][0] = fmaf(hval, w03.x, accg[i][0]);
            accg[i][1] = fmaf(hval, w03.y, accg[i][1]);
            accg[i][2] = fmaf(hval, w03.z, accg[i][2]);
            accg[i][3] = fmaf(hval, w03.w, accg[i][3]);
            accg[i][4] = fmaf(hval, w47.x, accg[i][4]);
            accg[i][5] = fmaf(hval, w47.y, accg[i][5]);
            accg[i][6] = fmaf(hval, w47.z, accg[i][6]);
            accg[i][7] = fmaf(hval, w47.w, accg[i][7]);
            accg[i][8] = fmaf(hval, t4.x,  accg[i][8]);
            accg[i][9] = fmaf(hval, t4.y,  accg[i][9]);
            accd[i][0] = fmaf(h2, v03.x, accd[i][0]);
            accd[i][1] = fmaf(h2, v03.y, accd[i][1]);
            accd[i][2] = fmaf(h2, v03.z, accd[i][2]);
            accd[i][3] = fmaf(h2, v03.w, accd[i][3]);
            accd[i][4] = fmaf(h2, v47.x, accd[i][4]);
            accd[i][5] = fmaf(h2, v47.y, accd[i][5]);
            accd[i][6] = fmaf(h2, v47.z, accd[i][6]);
            accd[i][7] = fmaf(h2, v47.w, accd[i][7]);
            accd[i][8] = fmaf(h2, t4.z,  accd[i][8]);
            accd[i][9] = fmaf(h2, t4.w,  accd[i][9]);
        }
        #pragma unroll
        for (int i = 0; i < 5; ++i) zc[i] = zn[i];
    }

    // reduce over the 16 kc lanes (butterfly stays inside 16-lane groups)
    #pragma unroll
    for (int i = 0; i < 5; ++i) {
        #pragma unroll
        for (int o = 0; o < ON; ++o) {
            float vg = accg[i][o], vd = accd[i][o];
            vg += __shfl_xor(vg, 1);  vd += __shfl_xor(vd, 1);
            vg += __shfl_xor(vg, 2);  vd += __shfl_xor(vd, 2);
            vg += __shfl_xor(vg, 4);  vd += __shfl_xor(vd, 4);
            vg += __shfl_xor(vg, 8);  vd += __shfl_xor(vd, 8);
            accg[i][o] = vg; accd[i][o] = vd;
        }
    }

    // epilogue: relu(g3 + sqrt(d3)*z3), softmax over 10, accumulate over this
    // thread's 5 MC rows. Only kc==0 lanes carry it.
    if (kc == 0) {
        float psum[ON];
        #pragma unroll
        for (int o = 0; o < ON; ++o) psum[o] = 0.0f;
        #pragma unroll 1
        for (int i = 0; i < 5; ++i) {
            int m = rg + 20 * i;
            const float* z3p = zeta3 + ((size_t)(g * MCN + m) * BN + b) * ON;
            float ov[ON];
            float mx = 0.0f;
            #pragma unroll
            for (int o = 0; o < ON; ++o) {
                float v = fmaf(sqrtf(accd[i][o]), z3p[o], accg[i][o]);
                v = fmaxf(v, 0.0f);
                ov[o] = v;
                mx = fmaxf(mx, v);
            }
            float se = 0.0f;
            #pragma unroll
            for (int o = 0; o < ON; ++o) { float e = __expf(ov[o] - mx); ov[o] = e; se += e; }
            float r = 1.0f / se;
            #pragma unroll
            for (int o = 0; o < ON; ++o) psum[o] = fmaf(ov[o], r, psum[o]);
        }
        #pragma unroll
        for (int o = 0; o < ON; ++o) outsh[rg][o] = psum[o];
    }
    __syncthreads();
    if (t < ON) {
        float s = 0.0f;
        #pragma unroll
        for (int r = 0; r < 20; ++r) s += outsh[r][t];
        out[b * (GN * ON) + g * ON + t] = s * (1.0f / MCN);
    }
}

extern "C" void kernel_launch(void* const* d_in, const int* in_sizes, int n_in,
                              void* d_out, int out_size, void* d_ws, size_t ws_size,
                              hipStream_t stream) {
    const float* x      = (const float*)d_in[0];
    const float* mu1    = (const float*)d_in[1];
    const float* sigma1 = (const float*)d_in[2];
    const float* mu3    = (const float*)d_in[3];
    const float* sigma3 = (const float*)d_in[4];
    const float* zeta1  = (const float*)d_in[5];
    const float* zeta3  = (const float*)d_in[6];
    // d_in[7] = num (always 3 -> G = 4, baked into GN)

    float* ws  = (float*)d_ws;
    float* xT  = ws;                       // 456*512  = 233472
    float* xxT = xT  + INN * BN;           // 233472
    float* sp1 = xxT + INN * BN;           // 4*456*400 = 729600
    float* A   = sp1 + GN * INN * HN;      // 4*512*400 = 819200
    float* S   = A   + GN * BN * HN;       // 819200
    float* out = (float*)d_out;            // 512*40

    k_transpose<<<dim3(8, 8), 256, 0, stream>>>(x, xT, xxT);
    k_sp1<<<dim3((GN * INN * HN / 4 + 255) / 256), 256, 0, stream>>>(sigma1, sp1);
    k_layer1<<<dim3(16, 7, GN), 256, 0, stream>>>(xT, xxT, mu1, sp1, A, S);
    k_layer2<<<dim3(BN, GN), 320, 0, stream>>>(A, S, mu3, sigma3, zeta1, zeta3, out);
}

// Round 2
// 666.168 us; speedup vs baseline: 1.2680x; 1.2680x over previous
//
#include <hip/hip_runtime.h>
#include <math.h>

#define GN  4
#define MCN 100
#define BN  512
#define INN 456
#define HN  400
#define ON  10

// softplus(s)^2, numerically stable
__device__ __forceinline__ float sp2f(float s) {
    float l = log1pf(__expf(-fabsf(s)));
    float r = fmaxf(s, 0.0f) + l;
    return r * r;
}

// ---------------- kernel: zero the output (atomicAdd target) ----------------
__global__ __launch_bounds__(256) void k_zero(float* __restrict__ out) {
    int i = blockIdx.x * 256 + threadIdx.x;
    if (i < BN * GN * ON) out[i] = 0.0f;
}

// ---------------- kernel 0a: x -> xT, x^2 -> xxT (tiled transpose) ----------------
__global__ __launch_bounds__(256) void k_transpose(
    const float* __restrict__ x, float* __restrict__ xT, float* __restrict__ xxT) {
    __shared__ float tile[64][65];
    int it = blockIdx.x;           // i tile (8 tiles, tail: 456 = 7*64 + 8)
    int bt = blockIdx.y;           // b tile (8 tiles of 64)
    int tx = threadIdx.x & 63;
    int ty = threadIdx.x >> 6;     // 0..3
    int i_in = it * 64 + tx;
    #pragma unroll
    for (int r = 0; r < 16; ++r) {
        int row = r * 4 + ty;
        int b = bt * 64 + row;
        tile[row][tx] = (i_in < INN) ? x[b * INN + i_in] : 0.0f;
    }
    __syncthreads();
    #pragma unroll
    for (int r = 0; r < 16; ++r) {
        int row = r * 4 + ty;
        int i = it * 64 + row;
        if (i < INN) {
            float v = tile[tx][row];           // stride 65 -> conflict-free
            xT[i * BN + bt * 64 + tx]  = v;
            xxT[i * BN + bt * 64 + tx] = v * v;
        }
    }
}

// ---------------- kernel 0b: sp1 = softplus(sigma1)^2 ----------------
__global__ __launch_bounds__(256) void k_sp1(
    const float* __restrict__ sigma1, float* __restrict__ sp1) {
    int idx = blockIdx.x * 256 + threadIdx.x;
    const int n4 = GN * INN * HN / 4;   // 182400
    if (idx < n4) {
        float4 s = ((const float4*)sigma1)[idx];
        float4 o;
        o.x = sp2f(s.x); o.y = sp2f(s.y); o.z = sp2f(s.z); o.w = sp2f(s.w);
        ((float4*)sp1)[idx] = o;
    }
}

// ---------------- kernel 1: A = x@mu1, S = sqrt((x*x)@sp1) ----------------
// lane = h (coalesced mu1/sp1 vector loads). Each thread owns 4 consecutive b's:
// one wave-uniform float4 load of xT/xxT per k (vs 16 scalar loads in v1).
// Grid 896 blocks -> 3.5 waves/SIMD for latency overlap.
__global__ __launch_bounds__(256) void k_layer1(
    const float* __restrict__ xT, const float* __restrict__ xxT,
    const float* __restrict__ mu1, const float* __restrict__ sp1,
    float* __restrict__ A, float* __restrict__ S) {
    int bt = blockIdx.x;            // 0..31
    int ht = blockIdx.y;            // 0..6
    int g  = blockIdx.z;            // 0..3
    int lane = threadIdx.x & 63;
    int wv   = threadIdx.x >> 6;    // 0..3
    int h = ht * 64 + lane;
    bool hv = h < HN;
    int hc = hv ? h : (HN - 1);     // clamp so masked lanes stay in-bounds
    int b0 = __builtin_amdgcn_readfirstlane(bt * 16 + wv * 4);
    const float* mp = mu1 + (size_t)g * INN * HN + hc;
    const float* pp = sp1 + (size_t)g * INN * HN + hc;
    float accA[4] = {0.f, 0.f, 0.f, 0.f};
    float accD[4] = {0.f, 0.f, 0.f, 0.f};
    #pragma unroll 4
    for (int k = 0; k < INN; ++k) {
        float a = mp[(size_t)k * HN];
        float p = pp[(size_t)k * HN];
        float4 xv  = *(const float4*)(xT  + k * BN + b0);   // wave-uniform 16B
        float4 xxv = *(const float4*)(xxT + k * BN + b0);
        accA[0] = fmaf(a, xv.x,  accA[0]);
        accA[1] = fmaf(a, xv.y,  accA[1]);
        accA[2] = fmaf(a, xv.z,  accA[2]);
        accA[3] = fmaf(a, xv.w,  accA[3]);
        accD[0] = fmaf(p, xxv.x, accD[0]);
        accD[1] = fmaf(p, xxv.y, accD[1]);
        accD[2] = fmaf(p, xxv.z, accD[2]);
        accD[3] = fmaf(p, xxv.w, accD[3]);
    }
    if (hv) {
        #pragma unroll
        for (int j = 0; j < 4; ++j) {
            size_t o = ((size_t)g * BN + (b0 + j)) * HN + h;
            A[o] = accA[j];
            S[o] = sqrtf(accD[j]);
        }
    }
}

// ---------------- kernel 2: layer 2 + softmax + MC mean ----------------
// block = (b, g, mc-chunk). 256 threads = 16 row-groups (TM=4 MC rows) x 16 kc.
// Chunk c covers m = c*64 + rg + 16*i (i<4); rows >= 100 clamped+discarded.
// acc = 4*10*2 = 80 VGPRs -> no spill under __launch_bounds__(256,3).
// zeta1 direct from global: 16 kc-lanes x 64B contiguous runs, 4 runs/wave.
// Weights in LDS rows of 20 floats (80B stride -> 2-way aliasing = free),
// 5 x ds_read_b128 per k, amortized over 4 MC rows per thread.
__global__ __launch_bounds__(256, 3) void k_layer2(
    const float* __restrict__ A, const float* __restrict__ S,
    const float* __restrict__ mu3, const float* __restrict__ sigma3,
    const float* __restrict__ zeta1, const float* __restrict__ zeta3,
    float* __restrict__ out) {
    int b  = blockIdx.x;   // 0..511
    int g  = blockIdx.y;   // 0..3
    int mb = blockIdx.z * 64;   // mc chunk base: 0 or 64

    __shared__ float as_s[2 * HN];      // [h][2] = {A, S}
    __shared__ float wv_s[HN * 20];     // [h][20] = {w0..3, v0..3, w4..7, v4..7, w8,w9,v8,v9}
    __shared__ float outsh[16][ON];

    int t = threadIdx.x;

    // stage A,S (coalesced)
    for (int i = t; i < HN; i += 256) {
        size_t src = ((size_t)g * BN + b) * HN + i;
        as_s[2 * i]     = A[src];
        as_s[2 * i + 1] = S[src];
    }
    // stage mu3 and sp2(sigma3) into chunked layout
    for (int i = t; i < HN * ON; i += 256) {
        int h = i / ON, o = i % ON;
        int wslot = (o < 4) ? o       : (o < 8) ? (4 + o) : (8 + o);   // 0-3, 8-11, 16-17
        int vslot = (o < 4) ? (4 + o) : (o < 8) ? (8 + o) : (10 + o);  // 4-7, 12-15, 18-19
        size_t src = (size_t)(g * HN + h) * ON + o;
        wv_s[h * 20 + wslot] = mu3[src];
        wv_s[h * 20 + vslot] = sp2f(sigma3[src]);
    }
    __syncthreads();

    int rg = t >> 4;    // 0..15  (row group: m = mb + rg + 16*i)
    int kc = t & 15;    // 0..15  (k = kc + 16*j)

    float accg[4][ON], accd[4][ON];
    #pragma unroll
    for (int i = 0; i < 4; ++i)
        #pragma unroll
        for (int o = 0; o < ON; ++o) { accg[i][o] = 0.0f; accd[i][o] = 0.0f; }

    const float* zp[4];
    #pragma unroll
    for (int i = 0; i < 4; ++i) {
        int m = mb + rg + 16 * i;
        int mcl = m < MCN ? m : (MCN - 1);     // clamp loads; result discarded
        zp[i] = zeta1 + ((size_t)(g * MCN + mcl) * BN + b) * HN + kc;
    }

    // depth-1 prefetch pipeline over j
    float zc[4];
    #pragma unroll
    for (int i = 0; i < 4; ++i) zc[i] = zp[i][0];

    #pragma unroll 1
    for (int j = 0; j < 25; ++j) {
        float zn[4];
        if (j < 24) {
            #pragma unroll
            for (int i = 0; i < 4; ++i) zn[i] = zp[i][16 * (j + 1)];
        } else {
            #pragma unroll
            for (int i = 0; i < 4; ++i) zn[i] = 0.0f;
        }
        int k = kc + 16 * j;
        float2 as = *(const float2*)(as_s + 2 * k);
        const float* wr = wv_s + k * 20;
        float4 w03 = *(const float4*)(wr);
        float4 v03 = *(const float4*)(wr + 4);
        float4 w47 = *(const float4*)(wr + 8);
        float4 v47 = *(const float4*)(wr + 12);
        float4 t4  = *(const float4*)(wr + 16);  // w8 w9 v8 v9
        #pragma unroll
        for (int i = 0; i < 4; ++i) {
            float hval = fmaxf(0.0f, fmaf(as.y, zc[i], as.x));
            float h2 = hval * hval;
            accg[i][0] = fmaf(hval, w03.x, accg[i][0]);
            accg[i][1] = fmaf(hval, w03.y, accg[i][1]);
            accg[i][2] = fmaf(hval, w03.z, accg[i][2]);
            accg[i][3] = fmaf(hval, w03.w, accg[i][3]);
            accg[i][4] = fmaf(hval, w47.x, accg[i][4]);
            accg[i][5] = fmaf(hval, w47.y, accg[i][5]);
            accg[i][6] = fmaf(hval, w47.z, accg[i][6]);
            accg[i][7] = fmaf(hval, w47.w, accg[i][7]);
            accg[i][8] = fmaf(hval, t4.x,  accg[i][8]);
            accg[i][9] = fmaf(hval, t4.y,  accg[i][9]);
            accd[i][0] = fmaf(h2, v03.x, accd[i][0]);
            accd[i][1] = fmaf(h2, v03.y, accd[i][1]);
            accd[i][2] = fmaf(h2, v03.z, accd[i][2]);
            accd[i][3] = fmaf(h2, v03.w, accd[i][3]);
            accd[i][4] = fmaf(h2, v47.x, accd[i][4]);
            accd[i][5] = fmaf(h2, v47.y, accd[i][5]);
            accd[i][6] = fmaf(h2, v47.z, accd[i][6]);
            accd[i][7] = fmaf(h2, v47.w, accd[i][7]);
            accd[i][8] = fmaf(h2, t4.z,  accd[i][8]);
            accd[i][9] = fmaf(h2, t4.w,  accd[i][9]);
        }
        #pragma unroll
        for (int i = 0; i < 4; ++i) zc[i] = zn[i];
    }

    // reduce over the 16 kc lanes (butterfly stays inside 16-lane groups)
    #pragma unroll
    for (int i = 0; i < 4; ++i) {
        #pragma unroll
        for (int o = 0; o < ON; ++o) {
            float vg = accg[i][o], vd = accd[i][o];
            vg += __shfl_xor(vg, 1);  vd += __shfl_xor(vd, 1);
            vg += __shfl_xor(vg, 2);  vd += __shfl_xor(vd, 2);
            vg += __shfl_xor(vg, 4);  vd += __shfl_xor(vd, 4);
            vg += __shfl_xor(vg, 8);  vd += __shfl_xor(vd, 8);
            accg[i][o] = vg; accd[i][o] = vd;
        }
    }

    // epilogue: relu(g3 + sqrt(d3)*z3), softmax over 10, accumulate this
    // thread's valid MC rows. FULLY UNROLLED (runtime-indexed acc arrays
    // force the whole array to scratch -- the Round-1 445us bug).
    if (kc == 0) {
        float psum[ON];
        #pragma unroll
        for (int o = 0; o < ON; ++o) psum[o] = 0.0f;
        #pragma unroll
        for (int i = 0; i < 4; ++i) {
            int m = mb + rg + 16 * i;
            if (m < MCN) {
                const float* z3p = zeta3 + ((size_t)(g * MCN + m) * BN + b) * ON;
                float ov[ON];
                float mx = 0.0f;
                #pragma unroll
                for (int o = 0; o < ON; ++o) {
                    float v = fmaf(sqrtf(accd[i][o]), z3p[o], accg[i][o]);
                    v = fmaxf(v, 0.0f);
                    ov[o] = v;
                    mx = fmaxf(mx, v);
                }
                float se = 0.0f;
                #pragma unroll
                for (int o = 0; o < ON; ++o) { float e = __expf(ov[o] - mx); ov[o] = e; se += e; }
                float r = 1.0f / se;
                #pragma unroll
                for (int o = 0; o < ON; ++o) psum[o] = fmaf(ov[o], r, psum[o]);
            }
        }
        #pragma unroll
        for (int o = 0; o < ON; ++o) outsh[rg][o] = psum[o];
    }
    __syncthreads();
    if (t < ON) {
        float s = 0.0f;
        #pragma unroll
        for (int r = 0; r < 16; ++r) s += outsh[r][t];
        atomicAdd(&out[b * (GN * ON) + g * ON + t], s * (1.0f / MCN));
    }
}

extern "C" void kernel_launch(void* const* d_in, const int* in_sizes, int n_in,
                              void* d_out, int out_size, void* d_ws, size_t ws_size,
                              hipStream_t stream) {
    const float* x      = (const float*)d_in[0];
    const float* mu1    = (const float*)d_in[1];
    const float* sigma1 = (const float*)d_in[2];
    const float* mu3    = (const float*)d_in[3];
    const float* sigma3 = (const float*)d_in[4];
    const float* zeta1  = (const float*)d_in[5];
    const float* zeta3  = (const float*)d_in[6];
    // d_in[7] = num (always 3 -> G = 4, baked into GN)

    float* ws  = (float*)d_ws;
    float* xT  = ws;                       // 456*512  = 233472
    float* xxT = xT  + INN * BN;           // 233472
    float* sp1 = xxT + INN * BN;           // 4*456*400 = 729600
    float* A   = sp1 + GN * INN * HN;      // 4*512*400 = 819200
    float* S   = A   + GN * BN * HN;       // 819200
    float* out = (float*)d_out;            // 512*40

    k_zero<<<dim3((BN * GN * ON + 255) / 256), 256, 0, stream>>>(out);
    k_transpose<<<dim3(8, 8), 256, 0, stream>>>(x, xT, xxT);
    k_sp1<<<dim3((GN * INN * HN / 4 + 255) / 256), 256, 0, stream>>>(sigma1, sp1);
    k_layer1<<<dim3(32, 7, GN), 256, 0, stream>>>(xT, xxT, mu1, sp1, A, S);
    k_layer2<<<dim3(BN, GN, 2), 256, 0, stream>>>(A, S, mu3, sigma3, zeta1, zeta3, out);
}